// Round 6
// baseline (1802.004 us; speedup 1.0000x reference)
//
#include <hip/hip_runtime.h>
#include <hip/hip_bf16.h>

#define B_ 32
#define T_ 512
#define F_ 9
#define H_ 64
#define P_ 84
#define LE_ 510
#define LBL_ 10

struct CombT { int c[P_][3]; };
__host__ __device__ constexpr CombT make_combs() {
    CombT t{}; int n = 0;
    for (int a = 0; a < F_; ++a)
        for (int b = a + 1; b < F_; ++b)
            for (int c = b + 1; c < F_; ++c) { t.c[n][0] = a; t.c[n][1] = b; t.c[n][2] = c; ++n; }
    return t;
}
constexpr CombT COMB_H = make_combs();

// ---------------------------------------------------------------------------
// Kernel A: A[h][f*3+k] = sum_p va_w1[p] * sum_i [comb[p][i]==f] w[p,h,i,k]
//           Abias[h]    = va_b1[h] + sum_p va_w1[p]*conv_b[p,h]
// ---------------------------------------------------------------------------
__global__ __launch_bounds__(256) void precomp_kernel(
    const float* __restrict__ conv_w, const float* __restrict__ conv_b,
    const float* __restrict__ va_w1, const float* __restrict__ va_b1,
    float* __restrict__ A, float* __restrict__ Abias)
{
    __shared__ float sacc[256][28];
    int tid = threadIdx.x;
    int h = tid >> 2, q = tid & 3;            // 64 h  x  4 p-quarters
    for (int j = 0; j < 28; ++j) sacc[tid][j] = 0.f;
    for (int p = q * 21; p < (q + 1) * 21; ++p) {
        float w1 = va_w1[p];
        sacc[tid][27] += w1 * conv_b[p * H_ + h];
        const float* wp = conv_w + p * (H_ * 9) + h * 9;
        for (int i = 0; i < 3; ++i) {
            int f = COMB_H.c[p][i];
            for (int k = 0; k < 3; ++k) sacc[tid][f * 3 + k] += w1 * wp[i * 3 + k];
        }
    }
    __syncthreads();
    if (q == 0) {
        for (int j = 0; j < 27; ++j)
            A[h * 27 + j] = sacc[tid][j] + sacc[tid + 1][j] + sacc[tid + 2][j] + sacc[tid + 3][j];
        Abias[h] = va_b1[h] + sacc[tid][27] + sacc[tid + 1][27] + sacc[tid + 2][27] + sacc[tid + 3][27];
    }
}

// ---------------------------------------------------------------------------
// transpose_kernel: cwT[p][j][h], j=0..8 taps (i*3+k), j=9 = bias.
// ---------------------------------------------------------------------------
__global__ __launch_bounds__(512) void transpose_kernel(
    const float* __restrict__ conv_w, const float* __restrict__ conv_b,
    float* __restrict__ cwT)
{
    int i = blockIdx.x * 512 + threadIdx.x;      // 84*640 = 53760
    if (i >= P_ * 640) return;
    int p = i / 640, r = i - p * 640;
    int j = r >> 6, h = r & 63;
    cwT[i] = (j < 9) ? conv_w[(p * H_ + h) * 9 + j] : conv_b[p * H_ + h];
}

// ---------------------------------------------------------------------------
// attn_kernel: per (ltile, b), 1024 threads (16 waves), lane = l.
// t1 (via A) -> t2 -> softmax -> store aw[b,lt,p,l] (normalized weights).
// ---------------------------------------------------------------------------
__global__ __launch_bounds__(1024) void attn_kernel(
    const float* __restrict__ x,
    const float* __restrict__ va_w2, const float* __restrict__ va_b2,
    const float* __restrict__ A, const float* __restrict__ Abias,
    float* __restrict__ aw)
{
    __shared__ float xs[66 * 9];
    __shared__ float t1s[64][65];
    __shared__ float t2s[64][85];

    const int b = blockIdx.y;
    const int lt = blockIdx.x;
    const int l0 = lt * 64;
    const int tid = threadIdx.x;
    const int ln = tid & 63;
    const int wv = tid >> 6;            // 0..15

    int maxidx = (T_ - l0) * F_; if (maxidx > 66 * F_) maxidx = 66 * F_;
    for (int i = tid; i < 66 * F_; i += 1024)
        xs[i] = (i < maxidx) ? x[b * (T_ * F_) + l0 * F_ + i] : 0.f;
    __syncthreads();

    float xw[27];
#pragma unroll
    for (int k = 0; k < 3; ++k)
#pragma unroll
        for (int f = 0; f < F_; ++f) xw[k * 9 + f] = xs[(ln + k) * F_ + f];

    // t1: wave wv covers h = wv*4 .. wv*4+3
#pragma unroll
    for (int hh = 0; hh < 4; ++hh) {
        int h = wv * 4 + hh;
        const float* Ah = A + h * 27;
        float s = Abias[h];
#pragma unroll
        for (int f = 0; f < F_; ++f)
#pragma unroll
            for (int k = 0; k < 3; ++k) s = fmaf(xw[k * 9 + f], Ah[f * 3 + k], s);
        t1s[ln][h] = fmaxf(s, 0.f);
    }
    __syncthreads();

    // t2: wave wv covers a p-slice
    const int cnt = (wv < 4) ? 6 : 5;
    const int p0 = (wv < 4) ? wv * 6 : 24 + (wv - 4) * 5;
    {
        float t2acc[6];
#pragma unroll
        for (int j = 0; j < 6; ++j) t2acc[j] = (j < cnt) ? va_b2[p0 + j] : 0.f;
        for (int h = 0; h < H_; ++h) {
            float tv = t1s[ln][h];
            const float* w2h = va_w2 + h * P_ + p0;
#pragma unroll
            for (int j = 0; j < 6; ++j)
                if (j < cnt) t2acc[j] = fmaf(tv, w2h[j], t2acc[j]);
        }
#pragma unroll
        for (int j = 0; j < 6; ++j)
            if (j < cnt) t2s[ln][p0 + j] = fmaxf(t2acc[j], 0.f);
    }
    __syncthreads();

    float mx = -1e30f;
    for (int p = 0; p < P_; ++p) mx = fmaxf(mx, t2s[ln][p]);
    float sum = 0.f;
    for (int p = 0; p < P_; ++p) sum += __expf(t2s[ln][p] - mx);
    float inv = 1.f / sum;

    const int awbase = (b * 8 + lt) * P_;
#pragma unroll
    for (int j = 0; j < 6; ++j)
        if (j < cnt)
            aw[(awbase + p0 + j) * 64 + ln] = __expf(t2s[ln][p0 + j] - mx) * inv;
}

// ---------------------------------------------------------------------------
// passB_kernel v3: grid (lt2 16, b 32), 512 thr (8 waves).  LANE = h.
// Wave wv owns 4 l's (l = lt2*32 + wv*4 + j).  x rows in SGPRs (54, static
// indices via full p-unroll), weights coalesced per-lane VMEM from cwT,
// aw via one uniform ds_read_b128 per p.  Writes vT[b][l][h] coalesced.
// ---------------------------------------------------------------------------
__global__ __launch_bounds__(512, 4) void passB_kernel(
    const float* __restrict__ x,
    const float* __restrict__ cwT,
    const float* __restrict__ aw,
    float* __restrict__ vT)
{
    __shared__ float aws[P_ * 32];          // 10752 B

    const int lt2 = blockIdx.x;             // 0..15
    const int b   = blockIdx.y;
    const int lt  = lt2 >> 1, lh = lt2 & 1;
    const int l0  = lt2 * 32;
    const int tid = threadIdx.x;
    const int h   = tid & 63;
    const int wv  = __builtin_amdgcn_readfirstlane(tid >> 6);   // 0..7

    // ---- stage aw columns [l0, l0+32) : aws[p][c] ----
    const float* awsrc = aw + (b * 8 + lt) * (P_ * 64) + lh * 32;
    for (int i = tid; i < P_ * 32; i += 512) {
        int row = i >> 5, col = i & 31;
        aws[i] = awsrc[row * 64 + col];
    }
    __syncthreads();

    // ---- wave's x rows lw..lw+5 into sx (wave-uniform -> scalar regs) ----
    const int lw = l0 + wv * 4;
    float sx[54];
    {
        const float* xb = x + b * (T_ * F_);
#pragma unroll
        for (int r = 0; r < 6; ++r) {
            int row = lw + r; if (row > T_ - 1) row = T_ - 1;   // tail clamp (masked later)
            const float* xr = xb + row * F_;
#pragma unroll
            for (int f = 0; f < F_; ++f) sx[r * 9 + f] = xr[f];
        }
    }

    float acc0 = 0.f, acc1 = 0.f, acc2 = 0.f, acc3 = 0.f;
    const float* cwp = cwT + h;             // + (p*10 + j)*64
    const int wv4 = wv * 4;

#pragma unroll
    for (int p = 0; p < P_; ++p) {
        const int f0 = COMB_H.c[p][0];      // compile-time under unroll
        const int f1 = COMB_H.c[p][1];
        const int f2 = COMB_H.c[p][2];
        const float* wp = cwp + p * 640;
        const float w0 = wp[0],   w1 = wp[64],  w2 = wp[128];
        const float w3 = wp[192], w4 = wp[256], w5 = wp[320];
        const float w6 = wp[384], w7 = wp[448], w8 = wp[512];
        const float w9 = wp[576];           // bias
        const float4 apv = *reinterpret_cast<const float4*>(&aws[p * 32 + wv4]);

#pragma unroll
        for (int j = 0; j < 4; ++j) {
            float cv = w9;
            cv = fmaf(w0, sx[(j + 0) * 9 + f0], cv);
            cv = fmaf(w1, sx[(j + 1) * 9 + f0], cv);
            cv = fmaf(w2, sx[(j + 2) * 9 + f0], cv);
            cv = fmaf(w3, sx[(j + 0) * 9 + f1], cv);
            cv = fmaf(w4, sx[(j + 1) * 9 + f1], cv);
            cv = fmaf(w5, sx[(j + 2) * 9 + f1], cv);
            cv = fmaf(w6, sx[(j + 0) * 9 + f2], cv);
            cv = fmaf(w7, sx[(j + 1) * 9 + f2], cv);
            cv = fmaf(w8, sx[(j + 2) * 9 + f2], cv);
            const float ap = (j == 0) ? apv.x : (j == 1) ? apv.y : (j == 2) ? apv.z : apv.w;
            if (j == 0) acc0 = fmaf(ap, cv, acc0);
            else if (j == 1) acc1 = fmaf(ap, cv, acc1);
            else if (j == 2) acc2 = fmaf(ap, cv, acc2);
            else acc3 = fmaf(ap, cv, acc3);
        }
    }

    // ---- coalesced transposed store ----
#pragma unroll
    for (int j = 0; j < 4; ++j) {
        const int l = lw + j;
        const float a = (j == 0) ? acc0 : (j == 1) ? acc1 : (j == 2) ? acc2 : acc3;
        if (l < LE_) vT[(b * LE_ + l) * 64 + h] = a;
    }
}

// ---------------------------------------------------------------------------
// ta_kernel v3 (vT layout): one block per b, 512 threads (8 waves), lane=h.
// All v reads coalesced (h contiguous); cross-wave reduce via LDS.
// ---------------------------------------------------------------------------
__global__ __launch_bounds__(512) void ta_kernel(
    const float* __restrict__ vT,
    const float* __restrict__ ta_w1, const float* __restrict__ ta_b1,
    const float* __restrict__ ta_w2, const float* __restrict__ ta_b2,
    const float* __restrict__ fc_w, const float* __restrict__ fc_b,
    float* __restrict__ out)
{
    __shared__ float u1p[8][64];
    __shared__ float attns[512];
    __shared__ float red8[8];
    __shared__ float zsf[64];

    const int b = blockIdx.x;
    const int tid = threadIdx.x;
    const int h = tid & 63;
    const int wv = tid >> 6;             // 0..7
    const float* vb = vT + b * (LE_ * 64);

    // ---- u1 partials: wave wv takes l = wv, wv+8, ... (coalesced) ----
    {
        float s = 0.f;
        for (int l = wv; l < LE_; l += 8)
            s = fmaf(vb[l * 64 + h], ta_w1[l], s);
        u1p[wv][h] = s;
    }
    __syncthreads();
    if (tid < 64) {
        float t = u1p[0][tid] + u1p[1][tid] + u1p[2][tid] + u1p[3][tid]
                + u1p[4][tid] + u1p[5][tid] + u1p[6][tid] + u1p[7][tid];
        u1p[0][tid] = fmaxf(t + ta_b1[tid], 0.f);        // u1s lives in row 0
    }
    __syncthreads();

    // ---- u2[l] : thread = l, coalesced ta_w2 reads ----
    float val = -1e30f;
    if (tid < LE_) {
        float s0 = ta_b2[tid], s1 = 0.f, s2 = 0.f, s3 = 0.f;
#pragma unroll
        for (int hx = 0; hx < H_; hx += 4) {
            s0 = fmaf(u1p[0][hx + 0], ta_w2[(hx + 0) * LE_ + tid], s0);
            s1 = fmaf(u1p[0][hx + 1], ta_w2[(hx + 1) * LE_ + tid], s1);
            s2 = fmaf(u1p[0][hx + 2], ta_w2[(hx + 2) * LE_ + tid], s2);
            s3 = fmaf(u1p[0][hx + 3], ta_w2[(hx + 3) * LE_ + tid], s3);
        }
        val = fmaxf((s0 + s1) + (s2 + s3), 0.f);
    }

    // ---- block softmax over l ----
    float m = val;
#pragma unroll
    for (int off = 32; off > 0; off >>= 1) m = fmaxf(m, __shfl_xor(m, off));
    if (h == 0) red8[wv] = m;
    __syncthreads();
    float M = red8[0];
#pragma unroll
    for (int i = 1; i < 8; ++i) M = fmaxf(M, red8[i]);

    float e = (tid < LE_) ? __expf(val - M) : 0.f;
    float s = e;
#pragma unroll
    for (int off = 32; off > 0; off >>= 1) s += __shfl_xor(s, off);
    __syncthreads();
    if (h == 0) red8[wv] = s;
    __syncthreads();
    float S = red8[0];
#pragma unroll
    for (int i = 1; i < 8; ++i) S += red8[i];
    attns[tid] = e * (1.f / S);
    __syncthreads();

    // ---- z partials (same shape as u1, weights = attns) ----
    {
        float t = 0.f;
        for (int l = wv; l < LE_; l += 8)
            t = fmaf(vb[l * 64 + h], attns[l], t);
        u1p[wv][h] = t;
    }
    __syncthreads();
    if (tid < 64)
        zsf[tid] = u1p[0][tid] + u1p[1][tid] + u1p[2][tid] + u1p[3][tid]
                 + u1p[4][tid] + u1p[5][tid] + u1p[6][tid] + u1p[7][tid];
    __syncthreads();

    if (tid < LBL_) {
        float r = fc_b[tid];
#pragma unroll
        for (int hx = 0; hx < H_; ++hx) r = fmaf(zsf[hx], fc_w[tid * H_ + hx], r);
        out[b * LBL_ + tid] = r;
    }
}

extern "C" void kernel_launch(void* const* d_in, const int* in_sizes, int n_in,
                              void* d_out, int out_size, void* d_ws, size_t ws_size,
                              hipStream_t stream)
{
    const float* x      = (const float*)d_in[0];
    const float* conv_w = (const float*)d_in[1];
    const float* conv_b = (const float*)d_in[2];
    const float* va_w1  = (const float*)d_in[3];
    const float* va_b1  = (const float*)d_in[4];
    const float* va_w2  = (const float*)d_in[5];
    const float* va_b2  = (const float*)d_in[6];
    const float* ta_w1  = (const float*)d_in[7];
    const float* ta_b1  = (const float*)d_in[8];
    const float* ta_w2  = (const float*)d_in[9];
    const float* ta_b2  = (const float*)d_in[10];
    const float* fc_w   = (const float*)d_in[11];
    const float* fc_b   = (const float*)d_in[12];

    float* ws    = (float*)d_ws;
    float* A     = ws;                        // 1728
    float* Abias = ws + 1728;                 // 64
    float* aw    = ws + 2048;                 // 32*8*84*64 = 1,376,256
    float* cwT   = ws + 2048 + 1376256;       // 84*10*64  =    53,760
    float* vT    = ws + 2048 + 1376256 + 53760; // 32*510*64 = 1,044,480

    precomp_kernel<<<1, 256, 0, stream>>>(conv_w, conv_b, va_w1, va_b1, A, Abias);
    transpose_kernel<<<105, 512, 0, stream>>>(conv_w, conv_b, cwT);
    attn_kernel<<<dim3(8, B_), 1024, 0, stream>>>(x, va_w2, va_b2, A, Abias, aw);
    passB_kernel<<<dim3(16, B_), 512, 0, stream>>>(x, cwT, aw, vT);
    ta_kernel<<<B_, 512, 0, stream>>>(vT, ta_w1, ta_b1, ta_w2, ta_b2, fc_w, fc_b, (float*)d_out);
}

// Round 7
// 1159.020 us; speedup vs baseline: 1.5548x; 1.5548x over previous
//
#include <hip/hip_runtime.h>
#include <hip/hip_bf16.h>

#define B_ 32
#define T_ 512
#define F_ 9
#define H_ 64
#define P_ 84
#define LE_ 510
#define LBL_ 10

struct CombT { int c[P_][3]; };
__host__ __device__ constexpr CombT make_combs() {
    CombT t{}; int n = 0;
    for (int a = 0; a < F_; ++a)
        for (int b = a + 1; b < F_; ++b)
            for (int c = b + 1; c < F_; ++c) { t.c[n][0] = a; t.c[n][1] = b; t.c[n][2] = c; ++n; }
    return t;
}
constexpr CombT COMB_H = make_combs();

// ---------------------------------------------------------------------------
// Kernel A: A[h][f*3+k] = sum_p va_w1[p] * sum_i [comb[p][i]==f] w[p,h,i,k]
//           Abias[h]    = va_b1[h] + sum_p va_w1[p]*conv_b[p,h]
// ---------------------------------------------------------------------------
__global__ __launch_bounds__(256) void precomp_kernel(
    const float* __restrict__ conv_w, const float* __restrict__ conv_b,
    const float* __restrict__ va_w1, const float* __restrict__ va_b1,
    float* __restrict__ A, float* __restrict__ Abias)
{
    __shared__ float sacc[256][28];
    int tid = threadIdx.x;
    int h = tid >> 2, q = tid & 3;            // 64 h  x  4 p-quarters
    for (int j = 0; j < 28; ++j) sacc[tid][j] = 0.f;
    for (int p = q * 21; p < (q + 1) * 21; ++p) {
        float w1 = va_w1[p];
        sacc[tid][27] += w1 * conv_b[p * H_ + h];
        const float* wp = conv_w + p * (H_ * 9) + h * 9;
        for (int i = 0; i < 3; ++i) {
            int f = COMB_H.c[p][i];
            for (int k = 0; k < 3; ++k) sacc[tid][f * 3 + k] += w1 * wp[i * 3 + k];
        }
    }
    __syncthreads();
    if (q == 0) {
        for (int j = 0; j < 27; ++j)
            A[h * 27 + j] = sacc[tid][j] + sacc[tid + 1][j] + sacc[tid + 2][j] + sacc[tid + 3][j];
        Abias[h] = va_b1[h] + sacc[tid][27] + sacc[tid + 1][27] + sacc[tid + 2][27] + sacc[tid + 3][27];
    }
}

// ---------------------------------------------------------------------------
// transpose_kernel: cwT2[p][h][12]: j=0..8 taps (i*3+k), j=9 bias, j=10,11 pad.
// Per-lane contiguous 48 B -> 3x dwordx4 in passB.
// ---------------------------------------------------------------------------
__global__ __launch_bounds__(512) void transpose_kernel(
    const float* __restrict__ conv_w, const float* __restrict__ conv_b,
    float* __restrict__ cwT2)
{
    int i = blockIdx.x * 512 + threadIdx.x;      // 84*768 = 64512
    if (i >= P_ * 768) return;
    int p = i / 768, r = i - p * 768;
    int h = r / 12, j = r - h * 12;
    float val = 0.f;
    if (j < 9) val = conv_w[(p * H_ + h) * 9 + j];
    else if (j == 9) val = conv_b[p * H_ + h];
    cwT2[i] = val;
}

// ---------------------------------------------------------------------------
// attn_kernel: per (ltile, b), 1024 threads (16 waves), lane = l.
// t1 (via A) -> t2 -> softmax -> store aw[b,lt,p,l] (normalized weights).
// ---------------------------------------------------------------------------
__global__ __launch_bounds__(1024) void attn_kernel(
    const float* __restrict__ x,
    const float* __restrict__ va_w2, const float* __restrict__ va_b2,
    const float* __restrict__ A, const float* __restrict__ Abias,
    float* __restrict__ aw)
{
    __shared__ float xs[66 * 9];
    __shared__ float t1s[64][65];
    __shared__ float t2s[64][85];

    const int b = blockIdx.y;
    const int lt = blockIdx.x;
    const int l0 = lt * 64;
    const int tid = threadIdx.x;
    const int ln = tid & 63;
    const int wv = tid >> 6;            // 0..15

    int maxidx = (T_ - l0) * F_; if (maxidx > 66 * F_) maxidx = 66 * F_;
    for (int i = tid; i < 66 * F_; i += 1024)
        xs[i] = (i < maxidx) ? x[b * (T_ * F_) + l0 * F_ + i] : 0.f;
    __syncthreads();

    float xw[27];
#pragma unroll
    for (int k = 0; k < 3; ++k)
#pragma unroll
        for (int f = 0; f < F_; ++f) xw[k * 9 + f] = xs[(ln + k) * F_ + f];

    // t1: wave wv covers h = wv*4 .. wv*4+3
#pragma unroll
    for (int hh = 0; hh < 4; ++hh) {
        int h = wv * 4 + hh;
        const float* Ah = A + h * 27;
        float s = Abias[h];
#pragma unroll
        for (int f = 0; f < F_; ++f)
#pragma unroll
            for (int k = 0; k < 3; ++k) s = fmaf(xw[k * 9 + f], Ah[f * 3 + k], s);
        t1s[ln][h] = fmaxf(s, 0.f);
    }
    __syncthreads();

    // t2: wave wv covers a p-slice
    const int cnt = (wv < 4) ? 6 : 5;
    const int p0 = (wv < 4) ? wv * 6 : 24 + (wv - 4) * 5;
    {
        float t2acc[6];
#pragma unroll
        for (int j = 0; j < 6; ++j) t2acc[j] = (j < cnt) ? va_b2[p0 + j] : 0.f;
        for (int h = 0; h < H_; ++h) {
            float tv = t1s[ln][h];
            const float* w2h = va_w2 + h * P_ + p0;
#pragma unroll
            for (int j = 0; j < 6; ++j)
                if (j < cnt) t2acc[j] = fmaf(tv, w2h[j], t2acc[j]);
        }
#pragma unroll
        for (int j = 0; j < 6; ++j)
            if (j < cnt) t2s[ln][p0 + j] = fmaxf(t2acc[j], 0.f);
    }
    __syncthreads();

    float mx = -1e30f;
    for (int p = 0; p < P_; ++p) mx = fmaxf(mx, t2s[ln][p]);
    float sum = 0.f;
    for (int p = 0; p < P_; ++p) sum += __expf(t2s[ln][p] - mx);
    float inv = 1.f / sum;

    const int awbase = (b * 8 + lt) * P_;
#pragma unroll
    for (int j = 0; j < 6; ++j)
        if (j < cnt)
            aw[(awbase + p0 + j) * 64 + ln] = __expf(t2s[ln][p0 + j] - mx) * inv;
}

// ---------------------------------------------------------------------------
// passB_kernel v4: grid (lt2 16, b 32), 512 thr (8 waves).  LANE = h.
// Wave wv owns 4 l's (l = lt2*32 + wv*4 + j).  x rows per-lane regs (54,
// static indices via full p-unroll), weights 3x dwordx4/lane/p from cwT2,
// aw via one uniform ds_read_b128 per p.  Writes vT[b][l][h] coalesced.
// launch_bounds(512,2): 256-VGPR cap -- do NOT force tighter (R6 spill).
// ---------------------------------------------------------------------------
__global__ __launch_bounds__(512, 2) void passB_kernel(
    const float* __restrict__ x,
    const float* __restrict__ cwT2,
    const float* __restrict__ aw,
    float* __restrict__ vT)
{
    __shared__ float aws[P_ * 32];          // 10752 B

    const int lt2 = blockIdx.x;             // 0..15
    const int b   = blockIdx.y;
    const int lt  = lt2 >> 1, lh = lt2 & 1;
    const int l0  = lt2 * 32;
    const int tid = threadIdx.x;
    const int h   = tid & 63;
    const int wv  = __builtin_amdgcn_readfirstlane(tid >> 6);   // 0..7

    // ---- stage aw columns [l0, l0+32) : aws[p][c] ----
    const float* awsrc = aw + (b * 8 + lt) * (P_ * 64) + lh * 32;
    for (int i = tid; i < P_ * 32; i += 512) {
        int row = i >> 5, col = i & 31;
        aws[i] = awsrc[row * 64 + col];
    }
    __syncthreads();

    // ---- wave's x rows lw..lw+5 (wave-uniform values, per-lane regs) ----
    const int lw = l0 + wv * 4;
    float sx[54];
    {
        const float* xb = x + b * (T_ * F_);
#pragma unroll
        for (int r = 0; r < 6; ++r) {
            int row = lw + r; if (row > T_ - 1) row = T_ - 1;   // tail clamp (store-masked)
            const float* xr = xb + row * F_;
#pragma unroll
            for (int f = 0; f < F_; ++f) sx[r * 9 + f] = xr[f];
        }
    }

    float acc0 = 0.f, acc1 = 0.f, acc2 = 0.f, acc3 = 0.f;
    const float* cwp = cwT2 + h * 12;       // + p*768
    const int wv4 = wv * 4;

#pragma unroll
    for (int p = 0; p < P_; ++p) {
        const int f0 = COMB_H.c[p][0];      // compile-time under unroll
        const int f1 = COMB_H.c[p][1];
        const int f2 = COMB_H.c[p][2];
        const float4 wA = *reinterpret_cast<const float4*>(&cwp[p * 768 + 0]);
        const float4 wB = *reinterpret_cast<const float4*>(&cwp[p * 768 + 4]);
        const float4 wC = *reinterpret_cast<const float4*>(&cwp[p * 768 + 8]);
        const float4 apv = *reinterpret_cast<const float4*>(&aws[p * 32 + wv4]);

        {   // j = 0
            float cv = wC.y;
            cv = fmaf(wA.x, sx[0 * 9 + f0], cv);
            cv = fmaf(wA.y, sx[1 * 9 + f0], cv);
            cv = fmaf(wA.z, sx[2 * 9 + f0], cv);
            cv = fmaf(wA.w, sx[0 * 9 + f1], cv);
            cv = fmaf(wB.x, sx[1 * 9 + f1], cv);
            cv = fmaf(wB.y, sx[2 * 9 + f1], cv);
            cv = fmaf(wB.z, sx[0 * 9 + f2], cv);
            cv = fmaf(wB.w, sx[1 * 9 + f2], cv);
            cv = fmaf(wC.x, sx[2 * 9 + f2], cv);
            acc0 = fmaf(apv.x, cv, acc0);
        }
        {   // j = 1
            float cv = wC.y;
            cv = fmaf(wA.x, sx[1 * 9 + f0], cv);
            cv = fmaf(wA.y, sx[2 * 9 + f0], cv);
            cv = fmaf(wA.z, sx[3 * 9 + f0], cv);
            cv = fmaf(wA.w, sx[1 * 9 + f1], cv);
            cv = fmaf(wB.x, sx[2 * 9 + f1], cv);
            cv = fmaf(wB.y, sx[3 * 9 + f1], cv);
            cv = fmaf(wB.z, sx[1 * 9 + f2], cv);
            cv = fmaf(wB.w, sx[2 * 9 + f2], cv);
            cv = fmaf(wC.x, sx[3 * 9 + f2], cv);
            acc1 = fmaf(apv.y, cv, acc1);
        }
        {   // j = 2
            float cv = wC.y;
            cv = fmaf(wA.x, sx[2 * 9 + f0], cv);
            cv = fmaf(wA.y, sx[3 * 9 + f0], cv);
            cv = fmaf(wA.z, sx[4 * 9 + f0], cv);
            cv = fmaf(wA.w, sx[2 * 9 + f1], cv);
            cv = fmaf(wB.x, sx[3 * 9 + f1], cv);
            cv = fmaf(wB.y, sx[4 * 9 + f1], cv);
            cv = fmaf(wB.z, sx[2 * 9 + f2], cv);
            cv = fmaf(wB.w, sx[3 * 9 + f2], cv);
            cv = fmaf(wC.x, sx[4 * 9 + f2], cv);
            acc2 = fmaf(apv.z, cv, acc2);
        }
        {   // j = 3
            float cv = wC.y;
            cv = fmaf(wA.x, sx[3 * 9 + f0], cv);
            cv = fmaf(wA.y, sx[4 * 9 + f0], cv);
            cv = fmaf(wA.z, sx[5 * 9 + f0], cv);
            cv = fmaf(wA.w, sx[3 * 9 + f1], cv);
            cv = fmaf(wB.x, sx[4 * 9 + f1], cv);
            cv = fmaf(wB.y, sx[5 * 9 + f1], cv);
            cv = fmaf(wB.z, sx[3 * 9 + f2], cv);
            cv = fmaf(wB.w, sx[4 * 9 + f2], cv);
            cv = fmaf(wC.x, sx[5 * 9 + f2], cv);
            acc3 = fmaf(apv.w, cv, acc3);
        }
    }

    // ---- coalesced transposed store ----
    if (lw + 0 < LE_) vT[(b * LE_ + lw + 0) * 64 + h] = acc0;
    if (lw + 1 < LE_) vT[(b * LE_ + lw + 1) * 64 + h] = acc1;
    if (lw + 2 < LE_) vT[(b * LE_ + lw + 2) * 64 + h] = acc2;
    if (lw + 3 < LE_) vT[(b * LE_ + lw + 3) * 64 + h] = acc3;
}

// ---------------------------------------------------------------------------
// ta_kernel v3 (vT layout): one block per b, 512 threads (8 waves), lane=h.
// ---------------------------------------------------------------------------
__global__ __launch_bounds__(512) void ta_kernel(
    const float* __restrict__ vT,
    const float* __restrict__ ta_w1, const float* __restrict__ ta_b1,
    const float* __restrict__ ta_w2, const float* __restrict__ ta_b2,
    const float* __restrict__ fc_w, const float* __restrict__ fc_b,
    float* __restrict__ out)
{
    __shared__ float u1p[8][64];
    __shared__ float attns[512];
    __shared__ float red8[8];
    __shared__ float zsf[64];

    const int b = blockIdx.x;
    const int tid = threadIdx.x;
    const int h = tid & 63;
    const int wv = tid >> 6;             // 0..7
    const float* vb = vT + b * (LE_ * 64);

    {
        float s = 0.f;
        for (int l = wv; l < LE_; l += 8)
            s = fmaf(vb[l * 64 + h], ta_w1[l], s);
        u1p[wv][h] = s;
    }
    __syncthreads();
    if (tid < 64) {
        float t = u1p[0][tid] + u1p[1][tid] + u1p[2][tid] + u1p[3][tid]
                + u1p[4][tid] + u1p[5][tid] + u1p[6][tid] + u1p[7][tid];
        u1p[0][tid] = fmaxf(t + ta_b1[tid], 0.f);        // u1s lives in row 0
    }
    __syncthreads();

    float val = -1e30f;
    if (tid < LE_) {
        float s0 = ta_b2[tid], s1 = 0.f, s2 = 0.f, s3 = 0.f;
#pragma unroll
        for (int hx = 0; hx < H_; hx += 4) {
            s0 = fmaf(u1p[0][hx + 0], ta_w2[(hx + 0) * LE_ + tid], s0);
            s1 = fmaf(u1p[0][hx + 1], ta_w2[(hx + 1) * LE_ + tid], s1);
            s2 = fmaf(u1p[0][hx + 2], ta_w2[(hx + 2) * LE_ + tid], s2);
            s3 = fmaf(u1p[0][hx + 3], ta_w2[(hx + 3) * LE_ + tid], s3);
        }
        val = fmaxf((s0 + s1) + (s2 + s3), 0.f);
    }

    float m = val;
#pragma unroll
    for (int off = 32; off > 0; off >>= 1) m = fmaxf(m, __shfl_xor(m, off));
    if (h == 0) red8[wv] = m;
    __syncthreads();
    float M = red8[0];
#pragma unroll
    for (int i = 1; i < 8; ++i) M = fmaxf(M, red8[i]);

    float e = (tid < LE_) ? __expf(val - M) : 0.f;
    float s = e;
#pragma unroll
    for (int off = 32; off > 0; off >>= 1) s += __shfl_xor(s, off);
    __syncthreads();
    if (h == 0) red8[wv] = s;
    __syncthreads();
    float S = red8[0];
#pragma unroll
    for (int i = 1; i < 8; ++i) S += red8[i];
    attns[tid] = e * (1.f / S);
    __syncthreads();

    {
        float t = 0.f;
        for (int l = wv; l < LE_; l += 8)
            t = fmaf(vb[l * 64 + h], attns[l], t);
        u1p[wv][h] = t;
    }
    __syncthreads();
    if (tid < 64)
        zsf[tid] = u1p[0][tid] + u1p[1][tid] + u1p[2][tid] + u1p[3][tid]
                 + u1p[4][tid] + u1p[5][tid] + u1p[6][tid] + u1p[7][tid];
    __syncthreads();

    if (tid < LBL_) {
        float r = fc_b[tid];
#pragma unroll
        for (int hx = 0; hx < H_; ++hx) r = fmaf(zsf[hx], fc_w[tid * H_ + hx], r);
        out[b * LBL_ + tid] = r;
    }
}

extern "C" void kernel_launch(void* const* d_in, const int* in_sizes, int n_in,
                              void* d_out, int out_size, void* d_ws, size_t ws_size,
                              hipStream_t stream)
{
    const float* x      = (const float*)d_in[0];
    const float* conv_w = (const float*)d_in[1];
    const float* conv_b = (const float*)d_in[2];
    const float* va_w1  = (const float*)d_in[3];
    const float* va_b1  = (const float*)d_in[4];
    const float* va_w2  = (const float*)d_in[5];
    const float* va_b2  = (const float*)d_in[6];
    const float* ta_w1  = (const float*)d_in[7];
    const float* ta_b1  = (const float*)d_in[8];
    const float* ta_w2  = (const float*)d_in[9];
    const float* ta_b2  = (const float*)d_in[10];
    const float* fc_w   = (const float*)d_in[11];
    const float* fc_b   = (const float*)d_in[12];

    float* ws    = (float*)d_ws;
    float* A     = ws;                          // 1728
    float* Abias = ws + 1728;                   // 64
    float* aw    = ws + 2048;                   // 32*8*84*64 = 1,376,256
    float* cwT2  = ws + 2048 + 1376256;         // 84*64*12  =    64,512
    float* vT    = ws + 2048 + 1376256 + 64512; // 32*510*64 = 1,044,480

    precomp_kernel<<<1, 256, 0, stream>>>(conv_w, conv_b, va_w1, va_b1, A, Abias);
    transpose_kernel<<<126, 512, 0, stream>>>(conv_w, conv_b, cwT2);
    attn_kernel<<<dim3(8, B_), 1024, 0, stream>>>(x, va_w2, va_b2, A, Abias, aw);
    passB_kernel<<<dim3(16, B_), 512, 0, stream>>>(x, cwT2, aw, vT);
    ta_kernel<<<B_, 512, 0, stream>>>(vT, ta_w1, ta_b1, ta_w2, ta_b2, fc_w, fc_b, (float*)d_out);
}

// Round 8
// 171.501 us; speedup vs baseline: 10.5072x; 6.7581x over previous
//
#include <hip/hip_runtime.h>
#include <hip/hip_bf16.h>

#define B_ 32
#define T_ 512
#define F_ 9
#define H_ 64
#define P_ 84
#define LE_ 510
#define LBL_ 10

struct CombT { int c[P_][3]; };
__host__ __device__ constexpr CombT make_combs() {
    CombT t{}; int n = 0;
    for (int a = 0; a < F_; ++a)
        for (int b = a + 1; b < F_; ++b)
            for (int c = b + 1; c < F_; ++c) { t.c[n][0] = a; t.c[n][1] = b; t.c[n][2] = c; ++n; }
    return t;
}
constexpr CombT COMB_H = make_combs();
__device__ __constant__ CombT COMB = make_combs();

// ---------------------------------------------------------------------------
// Kernel A: A[h][f*3+k] = sum_p va_w1[p] * sum_i [comb[p][i]==f] w[p,h,i,k]
//           Abias[h]    = va_b1[h] + sum_p va_w1[p]*conv_b[p,h]
// ---------------------------------------------------------------------------
__global__ __launch_bounds__(256) void precomp_kernel(
    const float* __restrict__ conv_w, const float* __restrict__ conv_b,
    const float* __restrict__ va_w1, const float* __restrict__ va_b1,
    float* __restrict__ A, float* __restrict__ Abias)
{
    __shared__ float sacc[256][28];
    int tid = threadIdx.x;
    int h = tid >> 2, q = tid & 3;            // 64 h  x  4 p-quarters
    for (int j = 0; j < 28; ++j) sacc[tid][j] = 0.f;
    for (int p = q * 21; p < (q + 1) * 21; ++p) {
        float w1 = va_w1[p];
        sacc[tid][27] += w1 * conv_b[p * H_ + h];
        const float* wp = conv_w + p * (H_ * 9) + h * 9;
        for (int i = 0; i < 3; ++i) {
            int f = COMB_H.c[p][i];
            for (int k = 0; k < 3; ++k) sacc[tid][f * 3 + k] += w1 * wp[i * 3 + k];
        }
    }
    __syncthreads();
    if (q == 0) {
        for (int j = 0; j < 27; ++j)
            A[h * 27 + j] = sacc[tid][j] + sacc[tid + 1][j] + sacc[tid + 2][j] + sacc[tid + 3][j];
        Abias[h] = va_b1[h] + sacc[tid][27] + sacc[tid + 1][27] + sacc[tid + 2][27] + sacc[tid + 3][27];
    }
}

// ---------------------------------------------------------------------------
// transpose_kernel: cwT2[p][h][12]: j=0..8 taps (i*3+k), j=9 bias, pad 2.
// Row start = (p*64+h)*48 B -> 16B-aligned; 3x dwordx4 per (p,h).
// ---------------------------------------------------------------------------
__global__ __launch_bounds__(512) void transpose_kernel(
    const float* __restrict__ conv_w, const float* __restrict__ conv_b,
    float* __restrict__ cwT2)
{
    int i = blockIdx.x * 512 + threadIdx.x;      // 84*768 = 64512
    if (i >= P_ * 768) return;
    int p = i / 768, r = i - p * 768;
    int h = r / 12, j = r - h * 12;
    float val = 0.f;
    if (j < 9) val = conv_w[(p * H_ + h) * 9 + j];
    else if (j == 9) val = conv_b[p * H_ + h];
    cwT2[i] = val;
}

// ---------------------------------------------------------------------------
// attn_kernel: per (ltile, b), 1024 threads (16 waves), lane = l.
// ---------------------------------------------------------------------------
__global__ __launch_bounds__(1024) void attn_kernel(
    const float* __restrict__ x,
    const float* __restrict__ va_w2, const float* __restrict__ va_b2,
    const float* __restrict__ A, const float* __restrict__ Abias,
    float* __restrict__ aw)
{
    __shared__ float xs[66 * 9];
    __shared__ float t1s[64][65];
    __shared__ float t2s[64][85];

    const int b = blockIdx.y;
    const int lt = blockIdx.x;
    const int l0 = lt * 64;
    const int tid = threadIdx.x;
    const int ln = tid & 63;
    const int wv = tid >> 6;            // 0..15

    int maxidx = (T_ - l0) * F_; if (maxidx > 66 * F_) maxidx = 66 * F_;
    for (int i = tid; i < 66 * F_; i += 1024)
        xs[i] = (i < maxidx) ? x[b * (T_ * F_) + l0 * F_ + i] : 0.f;
    __syncthreads();

    float xw[27];
#pragma unroll
    for (int k = 0; k < 3; ++k)
#pragma unroll
        for (int f = 0; f < F_; ++f) xw[k * 9 + f] = xs[(ln + k) * F_ + f];

#pragma unroll
    for (int hh = 0; hh < 4; ++hh) {
        int h = wv * 4 + hh;
        const float* Ah = A + h * 27;
        float s = Abias[h];
#pragma unroll
        for (int f = 0; f < F_; ++f)
#pragma unroll
            for (int k = 0; k < 3; ++k) s = fmaf(xw[k * 9 + f], Ah[f * 3 + k], s);
        t1s[ln][h] = fmaxf(s, 0.f);
    }
    __syncthreads();

    const int cnt = (wv < 4) ? 6 : 5;
    const int p0 = (wv < 4) ? wv * 6 : 24 + (wv - 4) * 5;
    {
        float t2acc[6];
#pragma unroll
        for (int j = 0; j < 6; ++j) t2acc[j] = (j < cnt) ? va_b2[p0 + j] : 0.f;
        for (int h = 0; h < H_; ++h) {
            float tv = t1s[ln][h];
            const float* w2h = va_w2 + h * P_ + p0;
#pragma unroll
            for (int j = 0; j < 6; ++j)
                if (j < cnt) t2acc[j] = fmaf(tv, w2h[j], t2acc[j]);
        }
#pragma unroll
        for (int j = 0; j < 6; ++j)
            if (j < cnt) t2s[ln][p0 + j] = fmaxf(t2acc[j], 0.f);
    }
    __syncthreads();

    float mx = -1e30f;
    for (int p = 0; p < P_; ++p) mx = fmaxf(mx, t2s[ln][p]);
    float sum = 0.f;
    for (int p = 0; p < P_; ++p) sum += __expf(t2s[ln][p] - mx);
    float inv = 1.f / sum;

    const int awbase = (b * 8 + lt) * P_;
#pragma unroll
    for (int j = 0; j < 6; ++j)
        if (j < cnt)
            aw[(awbase + p0 + j) * 64 + ln] = __expf(t2s[ln][p0 + j] - mx) * inv;
}

// ---------------------------------------------------------------------------
// passB_kernel v5 (= R4 structure + VMEM weight path):
// grid (lt 8, b 32, z 8), 256 thr (4 waves), lane = l.
// Waves split p (21 each), acc[8] per lane, cross-wave LDS reduce.
// x window: LDS xpack[f][ln][4], runtime-f ds_read_b128 (NO p-unroll).
// Weights: per-lane global_load_dwordx4 from cwT2 (wv kept divergent-typed
// so the compiler emits VMEM, not SMEM -- vmcnt pipelines precisely; the
// R5 SMEM path serialized on lgkmcnt drains at 27% VALUBusy).
// aw: per-lane coalesced global reads (L2-resident).
// ---------------------------------------------------------------------------
__global__ __launch_bounds__(256, 4) void passB_kernel(
    const float* __restrict__ x,
    const float* __restrict__ cwT2,
    const float* __restrict__ aw,
    float* __restrict__ v)
{
    __shared__ float xraw[66 * 9];           // 2376 B
    __shared__ float xpack[9 * 64 * 4];      // 9216 B  [f][ln][k, pad 4]
    __shared__ float red[4][8][64];          // 8192 B
    __shared__ int   cfs[P_ * 3];            // 1008 B

    const int lt = blockIdx.x;
    const int b  = blockIdx.y;
    const int z  = blockIdx.z;
    const int l0 = lt * 64;
    const int tid = threadIdx.x;
    const int ln  = tid & 63;
    const int wv  = tid >> 6;                // 0..3, deliberately NOT readfirstlane'd

    // ---- stage raw x + comb table ----
    int maxidx = (T_ - l0) * F_; if (maxidx > 66 * F_) maxidx = 66 * F_;
    for (int i = tid; i < 66 * F_; i += 256)
        xraw[i] = (i < maxidx) ? x[b * (T_ * F_) + l0 * F_ + i] : 0.f;
    for (int i = tid; i < P_ * 3; i += 256)
        cfs[i] = COMB.c[i / 3][i % 3];
    __syncthreads();
    for (int i = tid; i < 9 * 64; i += 256) {
        int f = i >> 6, l = i & 63;
        xpack[i * 4 + 0] = xraw[(l + 0) * F_ + f];
        xpack[i * 4 + 1] = xraw[(l + 1) * F_ + f];
        xpack[i * 4 + 2] = xraw[(l + 2) * F_ + f];
        xpack[i * 4 + 3] = 0.f;
    }
    __syncthreads();

    const int p0 = wv * 21;
    float acc[8];
#pragma unroll
    for (int i = 0; i < 8; ++i) acc[i] = 0.f;

    const float* awp   = aw + ((b * 8 + lt) * P_ + p0) * 64 + ln;
    const float* wbase = cwT2 + (p0 * 64 + z * 8) * 12;     // + pi*768 + hh*12

#pragma unroll 2
    for (int pi = 0; pi < 21; ++pi) {
        const int p = p0 + pi;
        const int f0 = cfs[p * 3 + 0];
        const int f1 = cfs[p * 3 + 1];
        const int f2 = cfs[p * 3 + 2];
        const float4 va = *reinterpret_cast<const float4*>(&xpack[(f0 * 64 + ln) * 4]);
        const float4 vb = *reinterpret_cast<const float4*>(&xpack[(f1 * 64 + ln) * 4]);
        const float4 vc = *reinterpret_cast<const float4*>(&xpack[(f2 * 64 + ln) * 4]);
        const float ap = awp[pi * 64];
        const float* wp = wbase + pi * 768;

#pragma unroll
        for (int hh = 0; hh < 8; ++hh) {
            const float4 wA = *reinterpret_cast<const float4*>(wp + hh * 12 + 0);
            const float4 wB = *reinterpret_cast<const float4*>(wp + hh * 12 + 4);
            const float4 wC = *reinterpret_cast<const float4*>(wp + hh * 12 + 8);
            float cv = wC.y;                 // bias (j=9)
            cv = fmaf(wA.x, va.x, cv);
            cv = fmaf(wA.y, va.y, cv);
            cv = fmaf(wA.z, va.z, cv);
            cv = fmaf(wA.w, vb.x, cv);
            cv = fmaf(wB.x, vb.y, cv);
            cv = fmaf(wB.y, vb.z, cv);
            cv = fmaf(wB.z, vc.x, cv);
            cv = fmaf(wB.w, vc.y, cv);
            cv = fmaf(wC.x, vc.z, cv);
            acc[hh] = fmaf(ap, cv, acc[hh]);
        }
    }

    // ---- cross-wave reduction ----
#pragma unroll
    for (int hh = 0; hh < 8; ++hh) red[wv][hh][ln] = acc[hh];
    __syncthreads();

    int valid = LE_ - l0; if (valid > 64) valid = 64;
    if (ln < valid) {
#pragma unroll
        for (int u = 0; u < 2; ++u) {
            const int hh = wv * 2 + u;
            float s = red[0][hh][ln] + red[1][hh][ln] + red[2][hh][ln] + red[3][hh][ln];
            v[(b * H_ + z * 8 + hh) * LE_ + l0 + ln] = s;
        }
    }
}

// ---------------------------------------------------------------------------
// ta_kernel v2 (proven R5): one block per b, 512 threads (8 waves).
// v layout [b][h][l]; all loads coalesced; shuffle reductions.
// ---------------------------------------------------------------------------
__global__ __launch_bounds__(512) void ta_kernel(
    const float* __restrict__ v,
    const float* __restrict__ ta_w1, const float* __restrict__ ta_b1,
    const float* __restrict__ ta_w2, const float* __restrict__ ta_b2,
    const float* __restrict__ fc_w, const float* __restrict__ fc_b,
    float* __restrict__ out)
{
    __shared__ float u1s[64];
    __shared__ float attns[512];
    __shared__ float red8[8];
    __shared__ float zs[64];

    const int b = blockIdx.x;
    const int tid = threadIdx.x;
    const int ln = tid & 63;
    const int wv = tid >> 6;             // 0..7
    const float* vb = v + b * (H_ * LE_);

#pragma unroll
    for (int hh = 0; hh < 8; ++hh) {
        const int h = wv * 8 + hh;
        const float* row = vb + h * LE_;
        float s = 0.f;
#pragma unroll
        for (int it = 0; it < 8; ++it) {
            int l = it * 64 + ln;
            if (l < LE_) s = fmaf(row[l], ta_w1[l], s);
        }
#pragma unroll
        for (int off = 32; off > 0; off >>= 1) s += __shfl_xor(s, off);
        if (ln == 0) u1s[h] = fmaxf(s + ta_b1[h], 0.f);
    }
    __syncthreads();

    float val = -1e30f;
    if (tid < LE_) {
        float s0 = ta_b2[tid], s1 = 0.f, s2 = 0.f, s3 = 0.f;
#pragma unroll
        for (int h = 0; h < H_; h += 4) {
            s0 = fmaf(u1s[h + 0], ta_w2[(h + 0) * LE_ + tid], s0);
            s1 = fmaf(u1s[h + 1], ta_w2[(h + 1) * LE_ + tid], s1);
            s2 = fmaf(u1s[h + 2], ta_w2[(h + 2) * LE_ + tid], s2);
            s3 = fmaf(u1s[h + 3], ta_w2[(h + 3) * LE_ + tid], s3);
        }
        val = fmaxf((s0 + s1) + (s2 + s3), 0.f);
    }

    float m = val;
#pragma unroll
    for (int off = 32; off > 0; off >>= 1) m = fmaxf(m, __shfl_xor(m, off));
    if (ln == 0) red8[wv] = m;
    __syncthreads();
    float M = red8[0];
#pragma unroll
    for (int i = 1; i < 8; ++i) M = fmaxf(M, red8[i]);

    float e = (tid < LE_) ? __expf(val - M) : 0.f;
    float s = e;
#pragma unroll
    for (int off = 32; off > 0; off >>= 1) s += __shfl_xor(s, off);
    __syncthreads();
    if (ln == 0) red8[wv] = s;
    __syncthreads();
    float S = red8[0];
#pragma unroll
    for (int i = 1; i < 8; ++i) S += red8[i];
    attns[tid] = e * (1.f / S);
    __syncthreads();

#pragma unroll
    for (int hh = 0; hh < 8; ++hh) {
        const int h = wv * 8 + hh;
        const float* row = vb + h * LE_;
        float t = 0.f;
#pragma unroll
        for (int it = 0; it < 8; ++it) {
            int l = it * 64 + ln;
            if (l < LE_) t = fmaf(row[l], attns[l], t);
        }
#pragma unroll
        for (int off = 32; off > 0; off >>= 1) t += __shfl_xor(t, off);
        if (ln == 0) zs[h] = t;
    }
    __syncthreads();

    if (tid < LBL_) {
        float r = fc_b[tid];
#pragma unroll
        for (int h = 0; h < H_; ++h) r = fmaf(zs[h], fc_w[tid * H_ + h], r);
        out[b * LBL_ + tid] = r;
    }
}

extern "C" void kernel_launch(void* const* d_in, const int* in_sizes, int n_in,
                              void* d_out, int out_size, void* d_ws, size_t ws_size,
                              hipStream_t stream)
{
    const float* x      = (const float*)d_in[0];
    const float* conv_w = (const float*)d_in[1];
    const float* conv_b = (const float*)d_in[2];
    const float* va_w1  = (const float*)d_in[3];
    const float* va_b1  = (const float*)d_in[4];
    const float* va_w2  = (const float*)d_in[5];
    const float* va_b2  = (const float*)d_in[6];
    const float* ta_w1  = (const float*)d_in[7];
    const float* ta_b1  = (const float*)d_in[8];
    const float* ta_w2  = (const float*)d_in[9];
    const float* ta_b2  = (const float*)d_in[10];
    const float* fc_w   = (const float*)d_in[11];
    const float* fc_b   = (const float*)d_in[12];

    float* ws    = (float*)d_ws;
    float* A     = ws;                          // 1728
    float* Abias = ws + 1728;                   // 64
    float* aw    = ws + 2048;                   // 32*8*84*64 = 1,376,256
    float* cwT2  = ws + 2048 + 1376256;         // 84*64*12  =    64,512
    float* v     = ws + 2048 + 1376256 + 64512; // 32*64*510 = 1,044,480

    precomp_kernel<<<1, 256, 0, stream>>>(conv_w, conv_b, va_w1, va_b1, A, Abias);
    transpose_kernel<<<126, 512, 0, stream>>>(conv_w, conv_b, cwT2);
    attn_kernel<<<dim3(8, B_), 1024, 0, stream>>>(x, va_w2, va_b2, A, Abias, aw);
    passB_kernel<<<dim3(8, B_, 8), 256, 0, stream>>>(x, cwT2, aw, v);
    ta_kernel<<<B_, 512, 0, stream>>>(v, ta_w1, ta_b1, ta_w2, ta_b2, fc_w, fc_b, (float*)d_out);
}

// Round 9
// 115.664 us; speedup vs baseline: 15.5796x; 1.4828x over previous
//
#include <hip/hip_runtime.h>
#include <hip/hip_bf16.h>

#define B_ 32
#define T_ 512
#define F_ 9
#define H_ 64
#define P_ 84
#define LE_ 510
#define LBL_ 10

struct CombT { int c[P_][3]; };
__host__ __device__ constexpr CombT make_combs() {
    CombT t{}; int n = 0;
    for (int a = 0; a < F_; ++a)
        for (int b = a + 1; b < F_; ++b)
            for (int c = b + 1; c < F_; ++c) { t.c[n][0] = a; t.c[n][1] = b; t.c[n][2] = c; ++n; }
    return t;
}
constexpr CombT COMB_H = make_combs();
__device__ __constant__ CombT COMB = make_combs();

// ---------------------------------------------------------------------------
// Kernel A: A[h][f*3+k] = sum_p va_w1[p] * sum_i [comb[p][i]==f] w[p,h,i,k]
//           Abias[h]    = va_b1[h] + sum_p va_w1[p]*conv_b[p,h]
// ---------------------------------------------------------------------------
__global__ __launch_bounds__(256) void precomp_kernel(
    const float* __restrict__ conv_w, const float* __restrict__ conv_b,
    const float* __restrict__ va_w1, const float* __restrict__ va_b1,
    float* __restrict__ A, float* __restrict__ Abias)
{
    __shared__ float sacc[256][28];
    int tid = threadIdx.x;
    int h = tid >> 2, q = tid & 3;            // 64 h  x  4 p-quarters
    for (int j = 0; j < 28; ++j) sacc[tid][j] = 0.f;
    for (int p = q * 21; p < (q + 1) * 21; ++p) {
        float w1 = va_w1[p];
        sacc[tid][27] += w1 * conv_b[p * H_ + h];
        const float* wp = conv_w + p * (H_ * 9) + h * 9;
        for (int i = 0; i < 3; ++i) {
            int f = COMB_H.c[p][i];
            for (int k = 0; k < 3; ++k) sacc[tid][f * 3 + k] += w1 * wp[i * 3 + k];
        }
    }
    __syncthreads();
    if (q == 0) {
        for (int j = 0; j < 27; ++j)
            A[h * 27 + j] = sacc[tid][j] + sacc[tid + 1][j] + sacc[tid + 2][j] + sacc[tid + 3][j];
        Abias[h] = va_b1[h] + sacc[tid][27] + sacc[tid + 1][27] + sacc[tid + 2][27] + sacc[tid + 3][27];
    }
}

// ---------------------------------------------------------------------------
// transpose_kernel: cwT2[p][h][12]: j=0..8 taps (i*3+k), j=9 bias, pad 2.
// (p,h) row = 48 B aligned; rows h, h+1 contiguous (96 B = 24 floats).
// ---------------------------------------------------------------------------
__global__ __launch_bounds__(512) void transpose_kernel(
    const float* __restrict__ conv_w, const float* __restrict__ conv_b,
    float* __restrict__ cwT2)
{
    int i = blockIdx.x * 512 + threadIdx.x;      // 84*768 = 64512
    if (i >= P_ * 768) return;
    int p = i / 768, r = i - p * 768;
    int h = r / 12, j = r - h * 12;
    float val = 0.f;
    if (j < 9) val = conv_w[(p * H_ + h) * 9 + j];
    else if (j == 9) val = conv_b[p * H_ + h];
    cwT2[i] = val;
}

// ---------------------------------------------------------------------------
// attn_kernel: per (ltile, b), 1024 threads (16 waves), lane = l.
// ---------------------------------------------------------------------------
__global__ __launch_bounds__(1024) void attn_kernel(
    const float* __restrict__ x,
    const float* __restrict__ va_w2, const float* __restrict__ va_b2,
    const float* __restrict__ A, const float* __restrict__ Abias,
    float* __restrict__ aw)
{
    __shared__ float xs[66 * 9];
    __shared__ float t1s[64][65];
    __shared__ float t2s[64][85];

    const int b = blockIdx.y;
    const int lt = blockIdx.x;
    const int l0 = lt * 64;
    const int tid = threadIdx.x;
    const int ln = tid & 63;
    const int wv = tid >> 6;            // 0..15

    int maxidx = (T_ - l0) * F_; if (maxidx > 66 * F_) maxidx = 66 * F_;
    for (int i = tid; i < 66 * F_; i += 1024)
        xs[i] = (i < maxidx) ? x[b * (T_ * F_) + l0 * F_ + i] : 0.f;
    __syncthreads();

    float xw[27];
#pragma unroll
    for (int k = 0; k < 3; ++k)
#pragma unroll
        for (int f = 0; f < F_; ++f) xw[k * 9 + f] = xs[(ln + k) * F_ + f];

#pragma unroll
    for (int hh = 0; hh < 4; ++hh) {
        int h = wv * 4 + hh;
        const float* Ah = A + h * 27;
        float s = Abias[h];
#pragma unroll
        for (int f = 0; f < F_; ++f)
#pragma unroll
            for (int k = 0; k < 3; ++k) s = fmaf(xw[k * 9 + f], Ah[f * 3 + k], s);
        t1s[ln][h] = fmaxf(s, 0.f);
    }
    __syncthreads();

    const int cnt = (wv < 4) ? 6 : 5;
    const int p0 = (wv < 4) ? wv * 6 : 24 + (wv - 4) * 5;
    {
        float t2acc[6];
#pragma unroll
        for (int j = 0; j < 6; ++j) t2acc[j] = (j < cnt) ? va_b2[p0 + j] : 0.f;
        for (int h = 0; h < H_; ++h) {
            float tv = t1s[ln][h];
            const float* w2h = va_w2 + h * P_ + p0;
#pragma unroll
            for (int j = 0; j < 6; ++j)
                if (j < cnt) t2acc[j] = fmaf(tv, w2h[j], t2acc[j]);
        }
#pragma unroll
        for (int j = 0; j < 6; ++j)
            if (j < cnt) t2s[ln][p0 + j] = fmaxf(t2acc[j], 0.f);
    }
    __syncthreads();

    float mx = -1e30f;
    for (int p = 0; p < P_; ++p) mx = fmaxf(mx, t2s[ln][p]);
    float sum = 0.f;
    for (int p = 0; p < P_; ++p) sum += __expf(t2s[ln][p] - mx);
    float inv = 1.f / sum;

    const int awbase = (b * 8 + lt) * P_;
#pragma unroll
    for (int j = 0; j < 6; ++j)
        if (j < cnt)
            aw[(awbase + p0 + j) * 64 + ln] = __expf(t2s[ln][p0 + j] - mx) * inv;
}

// ---------------------------------------------------------------------------
// passB_kernel v7: grid (lt 8, b 32, z2 32), 256 thr (4 waves), lane = l.
// Block covers 2 h's (h0 = z2*2); waves split p (21 each); LDS reduce.
// x window: LDS xpack[f][ln][4] runtime-f ds_read_b128 (no big unroll).
// Weights: wave-uniform s_loads (SMEM) with MANUAL DOUBLE-BUFFER: iter i+1's
// 6x s_load_dwordx4 are issued BEFORE iter i's FMA block, so the mandatory
// lgkmcnt(0) drain (SMEM is unordered) overlaps prior compute.  24 floats
// per iter -> A/B buffers fit in SGPRs.  32 waves/CU hides the residual.
// ---------------------------------------------------------------------------
#define PB_LOAD(D0, D1, D2, D3, D4, D5, PI) do {                                \
    const float* wq_ = wbase + (size_t)(PI) * 768;                              \
    D0 = *reinterpret_cast<const float4*>(wq_ + 0);                             \
    D1 = *reinterpret_cast<const float4*>(wq_ + 4);                             \
    D2 = *reinterpret_cast<const float4*>(wq_ + 8);                             \
    D3 = *reinterpret_cast<const float4*>(wq_ + 12);                            \
    D4 = *reinterpret_cast<const float4*>(wq_ + 16);                            \
    D5 = *reinterpret_cast<const float4*>(wq_ + 20);                            \
  } while (0)

#define PB_COMPUTE(PI, W0, W1, W2, W3, W4, W5) do {                             \
    const int pk = cfp[p0 + (PI)];                                              \
    const int f0 = pk & 31, f1 = (pk >> 5) & 31, f2 = pk >> 10;                 \
    const float4 va = *reinterpret_cast<const float4*>(&xpack[(f0 * 64 + ln) * 4]); \
    const float4 vb = *reinterpret_cast<const float4*>(&xpack[(f1 * 64 + ln) * 4]); \
    const float4 vc = *reinterpret_cast<const float4*>(&xpack[(f2 * 64 + ln) * 4]); \
    const float ap = awp[(PI) * 64];                                            \
    float cv0 = (W2).y;                                                         \
    cv0 = fmaf((W0).x, va.x, cv0); cv0 = fmaf((W0).y, va.y, cv0);               \
    cv0 = fmaf((W0).z, va.z, cv0); cv0 = fmaf((W0).w, vb.x, cv0);               \
    cv0 = fmaf((W1).x, vb.y, cv0); cv0 = fmaf((W1).y, vb.z, cv0);               \
    cv0 = fmaf((W1).z, vc.x, cv0); cv0 = fmaf((W1).w, vc.y, cv0);               \
    cv0 = fmaf((W2).x, vc.z, cv0);                                              \
    float cv1 = (W5).y;                                                         \
    cv1 = fmaf((W3).x, va.x, cv1); cv1 = fmaf((W3).y, va.y, cv1);               \
    cv1 = fmaf((W3).z, va.z, cv1); cv1 = fmaf((W3).w, vb.x, cv1);               \
    cv1 = fmaf((W4).x, vb.y, cv1); cv1 = fmaf((W4).y, vb.z, cv1);               \
    cv1 = fmaf((W4).z, vc.x, cv1); cv1 = fmaf((W4).w, vc.y, cv1);               \
    cv1 = fmaf((W5).x, vc.z, cv1);                                              \
    acc0 = fmaf(ap, cv0, acc0); acc1 = fmaf(ap, cv1, acc1);                     \
  } while (0)

__global__ __launch_bounds__(256, 8) void passB_kernel(
    const float* __restrict__ x,
    const float* __restrict__ cwT2,
    const float* __restrict__ aw,
    float* __restrict__ v)
{
    __shared__ float xraw[66 * 9];           // 2376 B
    __shared__ float xpack[9 * 64 * 4];      // 9216 B  [f][ln][k, pad 4]
    __shared__ int   cfp[P_];                //  336 B  packed f-triples
    __shared__ float red[4][2][64];          // 2048 B

    const int lt = blockIdx.x;
    const int b  = blockIdx.y;
    const int z2 = blockIdx.z;               // 0..31 -> h0 = z2*2
    const int l0 = lt * 64;
    const int tid = threadIdx.x;
    const int ln  = tid & 63;
    const int wvu = __builtin_amdgcn_readfirstlane(tid >> 6);   // 0..3 scalar

    // ---- stage raw x + packed comb table ----
    int maxidx = (T_ - l0) * F_; if (maxidx > 66 * F_) maxidx = 66 * F_;
    for (int i = tid; i < 66 * F_; i += 256)
        xraw[i] = (i < maxidx) ? x[b * (T_ * F_) + l0 * F_ + i] : 0.f;
    if (tid < P_)
        cfp[tid] = COMB.c[tid][0] | (COMB.c[tid][1] << 5) | (COMB.c[tid][2] << 10);
    __syncthreads();
    for (int i = tid; i < 9 * 64; i += 256) {
        int f = i >> 6, l = i & 63;
        xpack[i * 4 + 0] = xraw[(l + 0) * F_ + f];
        xpack[i * 4 + 1] = xraw[(l + 1) * F_ + f];
        xpack[i * 4 + 2] = xraw[(l + 2) * F_ + f];
        xpack[i * 4 + 3] = 0.f;
    }
    __syncthreads();

    const int p0 = wvu * 21;
    float acc0 = 0.f, acc1 = 0.f;

    const float* awp   = aw + ((b * 8 + lt) * P_ + p0) * 64 + ln;
    const float* wbase = cwT2 + (size_t)(p0 * 64 + z2 * 2) * 12;   // + pi*768

    float4 A0, A1, A2, A3, A4, A5, Bw0, Bw1, Bw2, Bw3, Bw4, Bw5;
    PB_LOAD(A0, A1, A2, A3, A4, A5, 0);

#pragma unroll 1
    for (int pi = 0; pi < 21; pi += 2) {
        if (pi + 1 < 21) PB_LOAD(Bw0, Bw1, Bw2, Bw3, Bw4, Bw5, pi + 1);
        PB_COMPUTE(pi, A0, A1, A2, A3, A4, A5);
        if (pi + 1 < 21) {
            if (pi + 2 < 21) PB_LOAD(A0, A1, A2, A3, A4, A5, pi + 2);
            PB_COMPUTE(pi + 1, Bw0, Bw1, Bw2, Bw3, Bw4, Bw5);
        }
    }

    // ---- cross-wave reduction (4 waves -> 2 h rows) ----
    red[wvu][0][ln] = acc0;
    red[wvu][1][ln] = acc1;
    __syncthreads();

    int valid = LE_ - l0; if (valid > 64) valid = 64;
    if (wvu < 2 && ln < valid) {
        float s = red[0][wvu][ln] + red[1][wvu][ln] + red[2][wvu][ln] + red[3][wvu][ln];
        v[(b * H_ + z2 * 2 + wvu) * LE_ + l0 + ln] = s;
    }
}

// ---------------------------------------------------------------------------
// ta_kernel v2 (proven R5): one block per b, 512 threads (8 waves).
// v layout [b][h][l]; all loads coalesced; shuffle reductions.
// ---------------------------------------------------------------------------
__global__ __launch_bounds__(512) void ta_kernel(
    const float* __restrict__ v,
    const float* __restrict__ ta_w1, const float* __restrict__ ta_b1,
    const float* __restrict__ ta_w2, const float* __restrict__ ta_b2,
    const float* __restrict__ fc_w, const float* __restrict__ fc_b,
    float* __restrict__ out)
{
    __shared__ float u1s[64];
    __shared__ float attns[512];
    __shared__ float red8[8];
    __shared__ float zs[64];

    const int b = blockIdx.x;
    const int tid = threadIdx.x;
    const int ln = tid & 63;
    const int wv = tid >> 6;             // 0..7
    const float* vb = v + b * (H_ * LE_);

#pragma unroll
    for (int hh = 0; hh < 8; ++hh) {
        const int h = wv * 8 + hh;
        const float* row = vb + h * LE_;
        float s = 0.f;
#pragma unroll
        for (int it = 0; it < 8; ++it) {
            int l = it * 64 + ln;
            if (l < LE_) s = fmaf(row[l], ta_w1[l], s);
        }
#pragma unroll
        for (int off = 32; off > 0; off >>= 1) s += __shfl_xor(s, off);
        if (ln == 0) u1s[h] = fmaxf(s + ta_b1[h], 0.f);
    }
    __syncthreads();

    float val = -1e30f;
    if (tid < LE_) {
        float s0 = ta_b2[tid], s1 = 0.f, s2 = 0.f, s3 = 0.f;
#pragma unroll
        for (int h = 0; h < H_; h += 4) {
            s0 = fmaf(u1s[h + 0], ta_w2[(h + 0) * LE_ + tid], s0);
            s1 = fmaf(u1s[h + 1], ta_w2[(h + 1) * LE_ + tid], s1);
            s2 = fmaf(u1s[h + 2], ta_w2[(h + 2) * LE_ + tid], s2);
            s3 = fmaf(u1s[h + 3], ta_w2[(h + 3) * LE_ + tid], s3);
        }
        val = fmaxf((s0 + s1) + (s2 + s3), 0.f);
    }

    float m = val;
#pragma unroll
    for (int off = 32; off > 0; off >>= 1) m = fmaxf(m, __shfl_xor(m, off));
    if (ln == 0) red8[wv] = m;
    __syncthreads();
    float M = red8[0];
#pragma unroll
    for (int i = 1; i < 8; ++i) M = fmaxf(M, red8[i]);

    float e = (tid < LE_) ? __expf(val - M) : 0.f;
    float s = e;
#pragma unroll
    for (int off = 32; off > 0; off >>= 1) s += __shfl_xor(s, off);
    __syncthreads();
    if (ln == 0) red8[wv] = s;
    __syncthreads();
    float S = red8[0];
#pragma unroll
    for (int i = 1; i < 8; ++i) S += red8[i];
    attns[tid] = e * (1.f / S);
    __syncthreads();

#pragma unroll
    for (int hh = 0; hh < 8; ++hh) {
        const int h = wv * 8 + hh;
        const float* row = vb + h * LE_;
        float t = 0.f;
#pragma unroll
        for (int it = 0; it < 8; ++it) {
            int l = it * 64 + ln;
            if (l < LE_) t = fmaf(row[l], attns[l], t);
        }
#pragma unroll
        for (int off = 32; off > 0; off >>= 1) t += __shfl_xor(t, off);
        if (ln == 0) zs[h] = t;
    }
    __syncthreads();

    if (tid < LBL_) {
        float r = fc_b[tid];
#pragma unroll
        for (int h = 0; h < H_; ++h) r = fmaf(zs[h], fc_w[tid * H_ + h], r);
        out[b * LBL_ + tid] = r;
    }
}

extern "C" void kernel_launch(void* const* d_in, const int* in_sizes, int n_in,
                              void* d_out, int out_size, void* d_ws, size_t ws_size,
                              hipStream_t stream)
{
    const float* x      = (const float*)d_in[0];
    const float* conv_w = (const float*)d_in[1];
    const float* conv_b = (const float*)d_in[2];
    const float* va_w1  = (const float*)d_in[3];
    const float* va_b1  = (const float*)d_in[4];
    const float* va_w2  = (const float*)d_in[5];
    const float* va_b2  = (const float*)d_in[6];
    const float* ta_w1  = (const float*)d_in[7];
    const float* ta_b1  = (const float*)d_in[8];
    const float* ta_w2  = (const float*)d_in[9];
    const float* ta_b2  = (const float*)d_in[10];
    const float* fc_w   = (const float*)d_in[11];
    const float* fc_b   = (const float*)d_in[12];

    float* ws    = (float*)d_ws;
    float* A     = ws;                          // 1728
    float* Abias = ws + 1728;                   // 64
    float* aw    = ws + 2048;                   // 32*8*84*64 = 1,376,256
    float* cwT2  = ws + 2048 + 1376256;         // 84*64*12  =    64,512
    float* v     = ws + 2048 + 1376256 + 64512; // 32*64*510 = 1,044,480

    precomp_kernel<<<1, 256, 0, stream>>>(conv_w, conv_b, va_w1, va_b1, A, Abias);
    transpose_kernel<<<126, 512, 0, stream>>>(conv_w, conv_b, cwT2);
    attn_kernel<<<dim3(8, B_), 1024, 0, stream>>>(x, va_w2, va_b2, A, Abias, aw);
    passB_kernel<<<dim3(8, B_, 32), 256, 0, stream>>>(x, cwT2, aw, v);
    ta_kernel<<<B_, 512, 0, stream>>>(v, ta_w1, ta_b1, ta_w2, ta_b2, fc_w, fc_b, (float*)d_out);
}